// Round 7
// baseline (232.218 us; speedup 1.0000x reference)
//
#include <hip/hip_runtime.h>

#define SEQ 2048
#define HD 64
#define NBH 24

// ---------------- workspace layout (proven rounds 5/6) ----------------
#define MB_OFF   0
#define MB_BYTES (32 * 32 * 512)                 // 512 KB: [qtb][kt][64 q-rows][u64 of k-bits]
#define QB_OFF   (MB_OFF + MB_BYTES)
#define QK_BYTES (NBH * SEQ * HD * 2)            // 6 MB bf16, plain 128B rows
#define KB_OFF   (QB_OFF + QK_BYTES)
#define VT_OFF   (KB_OFF + QK_BYTES)             // V^T pre-tiled: [bh][kt] 8KB tiles, d-major 128B rows
#define WS_NEED  ((size_t)(VT_OFF + QK_BYTES))   // ~18.5 MB

typedef __bf16 bfrag8 __attribute__((ext_vector_type(8)));
typedef __bf16 bf16x4 __attribute__((ext_vector_type(4)));
typedef float  floatx4 __attribute__((ext_vector_type(4)));

__device__ __forceinline__ floatx4 mfma_16x16x32(bfrag8 a, bfrag8 b, floatx4 c) {
    return __builtin_amdgcn_mfma_f32_16x16x32_bf16(a, b, c, 0, 0, 0);
}

// ================= prepass (byte-identical to rounds 5/6 — proven) =================
__global__ __launch_bounds__(256)
void prep_kernel(const float* __restrict__ qp, const float* __restrict__ kp,
                 const float* __restrict__ vp, const int* __restrict__ maskp,
                 unsigned char* __restrict__ ws)
{
    __shared__ __attribute__((aligned(16))) unsigned char parena[64 * 68 * 4];
    const int t = threadIdx.x;
    const int b = blockIdx.x;

    if (b < 1536) {
        int gt  = b * 256 + t;
        int row = gt >> 3;
        int c   = gt & 7;
        const floatx4* qs = (const floatx4*)(qp + row * 64 + c * 8);
        const floatx4* ks = (const floatx4*)(kp + row * 64 + c * 8);
        floatx4 q0 = qs[0], q1 = qs[1];
        floatx4 k0 = ks[0], k1 = ks[1];
        bfrag8 qpk, kpk;
        #pragma unroll
        for (int i = 0; i < 4; ++i) {
            qpk[i] = (__bf16)q0[i]; qpk[4 + i] = (__bf16)q1[i];
            kpk[i] = (__bf16)k0[i]; kpk[4 + i] = (__bf16)k1[i];
        }
        *(bfrag8*)(ws + QB_OFF + row * 128 + c * 16) = qpk;
        *(bfrag8*)(ws + KB_OFF + row * 128 + c * 16) = kpk;
    } else if (b < 2304) {
        int bb = b - 1536, bh = bb >> 5, kt = bb & 31;
        float* lf = (float*)parena;                 // [64 k][68 d]
        const floatx4* vg = (const floatx4*)(vp + (bh * SEQ + kt * 64) * 64);
        #pragma unroll
        for (int it = 0; it < 4; ++it) {
            int f = t + it * 256;
            int r = f >> 4, c4 = f & 15;
            floatx4 val = vg[f];
            #pragma unroll
            for (int i = 0; i < 4; ++i) lf[r * 68 + c4 * 4 + i] = val[i];
        }
        __syncthreads();
        int d = t >> 2, kseg = t & 3;
        unsigned char* tb = ws + VT_OFF + (size_t)(bh * 32 + kt) * 8192 + d * 128;
        #pragma unroll
        for (int jj = 0; jj < 2; ++jj) {
            bfrag8 pk;
            #pragma unroll
            for (int e = 0; e < 8; ++e)
                pk[e] = (__bf16)lf[(kseg * 16 + jj * 8 + e) * 68 + d];
            *(bfrag8*)(tb + (kseg * 2 + jj) * 16) = pk;
        }
    } else {
        int cc = b - 2304, qtb = cc >> 5, kt = cc & 31;
        const int w = t >> 6, lane = t & 63;
        #pragma unroll
        for (int it = 0; it < 16; ++it) {
            int rr = it * 4 + w;
            unsigned long long bl = __ballot(maskp[(qtb * 64 + rr) * SEQ + kt * 64 + lane] != 0);
            if (lane == 0)
                *(unsigned long long*)(ws + MB_OFF + (size_t)((qtb * 32 + kt) * 64 + rr) * 8) = bl;
        }
    }
}

// ================= main: K/V global-direct regs, k-split QK, b64 S-bridge =================
__global__ __launch_bounds__(256, 3)
void normattn_main(const unsigned char* __restrict__ ws,
                   const float* __restrict__ gammap, const float* __restrict__ betap,
                   float* __restrict__ outp)
{
    // shared S tile: [64 q][72 k-elems] bf16 (144B rows; pa b128 reads 16B-aligned)
    __shared__ __attribute__((aligned(16))) unsigned char sS[64 * 144];

    const int tid  = threadIdx.x;
    const int w    = tid >> 6;
    const int lane = tid & 63;
    const int quad = lane >> 4;
    const int l16  = lane & 15;
    const int qtb  = blockIdx.x;
    const int bh   = blockIdx.y;
    const int q0   = qtb * 64;

    const unsigned char* gKb = ws + KB_OFF + (size_t)(bh * SEQ) * 128;
    const unsigned char* gVb = ws + VT_OFF + (size_t)(bh * 32) * 8192;
    const unsigned char* gMb = ws + MB_OFF + (size_t)(qtb * 32) * 512;

    // Q fragments, register-resident, used as B-operand (round-5-proven addressing):
    // qb[qt][h] = Q[q0 + qt*16 + l16][h*32 + quad*8 + j]
    bfrag8 qb[4][2];
    #pragma unroll
    for (int qt = 0; qt < 4; ++qt) {
        const unsigned char* gQ = ws + QB_OFF + (size_t)(bh * SEQ + q0 + qt * 16 + l16) * 128 + quad * 16;
        qb[qt][0] = *(const bfrag8*)gQ;
        qb[qt][1] = *(const bfrag8*)(gQ + 64);
    }

    floatx4 acc[4];   // acc[nt][r] = O[q = q0 + w*16 + quad*4 + r][d = nt*16 + l16]  (round-6 meaning)
    #pragma unroll
    for (int i = 0; i < 4; ++i) acc[i] = (floatx4)0.0f;
    const int qrow_loc = w * 16 + quad * 4;

    // prefetch kt=0: K A-frags (wave's 16-k slice) + mask row-words
    bfrag8 ka0, ka1;
    unsigned long long mr[4];
    {
        const unsigned char* gK = gKb + (size_t)(w * 16 + l16) * 128 + quad * 16;
        ka0 = *(const bfrag8*)gK;
        ka1 = *(const bfrag8*)(gK + 64);
        #pragma unroll
        for (int qt = 0; qt < 4; ++qt)
            mr[qt] = *(const unsigned long long*)(gMb + (qt * 16 + l16) * 8);
    }

    for (int kt = 0; kt < 32; ++kt) {
        // ---- prefetch NEXT kt's K-frags + mask (consumed next iteration) ----
        const int ktn = (kt < 31) ? kt + 1 : 31;
        bfrag8 kn0, kn1;
        unsigned long long mrn[4];
        {
            const unsigned char* gK = gKb + (size_t)(ktn * 64 + w * 16 + l16) * 128 + quad * 16;
            kn0 = *(const bfrag8*)gK;
            kn1 = *(const bfrag8*)(gK + 64);
            #pragma unroll
            for (int qt = 0; qt < 4; ++qt)
                mrn[qt] = *(const unsigned long long*)(gMb + (size_t)ktn * 512 + (qt * 16 + l16) * 8);
        }
        // ---- V^T B-frags for THIS kt (round-5-proven formula), consumed after mid-barrier ----
        bfrag8 vb[4][2];
        {
            const unsigned char* gV = gVb + (size_t)kt * 8192;
            #pragma unroll
            for (int nt = 0; nt < 4; ++nt) {
                vb[nt][0] = *(const bfrag8*)(gV + (nt * 16 + l16) * 128 + quad * 16);
                vb[nt][1] = *(const bfrag8*)(gV + (nt * 16 + l16) * 128 + 64 + quad * 16);
            }
        }

        // ---- QK^T, swapped operands (k-split): st[r] = S[q0+qt*16+l16][kt*64 + w*16 + quad*4 + r] ----
        #pragma unroll
        for (int qt = 0; qt < 4; ++qt) {
            floatx4 st = (floatx4)0.0f;
            st = mfma_16x16x32(ka0, qb[qt][0], st);
            st = mfma_16x16x32(ka1, qb[qt][1], st);
            unsigned long long m4 = mr[qt] >> (w * 16 + quad * 4);
            bf16x4 pk;
            #pragma unroll
            for (int r = 0; r < 4; ++r) {
                float v = ((m4 >> r) & 1ull) ? st[r] : -10000.0f;
                pk[r] = (__bf16)v;
            }
            // 4 k-consecutive values -> one b64 write: row qt*16+l16, k-elem w*16+quad*4
            *(bf16x4*)(sS + (qt * 16 + l16) * 144 + w * 32 + quad * 8) = pk;
        }
        asm volatile("s_waitcnt lgkmcnt(0)" ::: "memory");
        asm volatile("s_barrier" ::: "memory");

        // ---- PV (round-6 semantics): acc[nt] += S[w-slice][k] * V^T ----
        #pragma unroll
        for (int kc2 = 0; kc2 < 2; ++kc2) {
            bfrag8 pa = *(const bfrag8*)(sS + (w * 16 + l16) * 144 + kc2 * 64 + quad * 16);
            #pragma unroll
            for (int nt = 0; nt < 4; ++nt)
                acc[nt] = mfma_16x16x32(pa, vb[nt][kc2], acc[nt]);
        }
        asm volatile("s_waitcnt lgkmcnt(0)" ::: "memory");
        asm volatile("s_barrier" ::: "memory");

        ka0 = kn0; ka1 = kn1;
        #pragma unroll
        for (int qt = 0; qt < 4; ++qt) mr[qt] = mrn[qt];
    }

    // ---- LayerNorm epilogue (round-6-proven, verbatim) ----
    float g[4], bt[4];
    #pragma unroll
    for (int nt = 0; nt < 4; ++nt) {
        g[nt]  = gammap[nt * 16 + l16];
        bt[nt] = betap[nt * 16 + l16];
    }
    #pragma unroll
    for (int r = 0; r < 4; ++r) {
        float s = 0.0f, s2 = 0.0f;
        #pragma unroll
        for (int nt = 0; nt < 4; ++nt) { float x = acc[nt][r]; s += x; s2 += x * x; }
        #pragma unroll
        for (int off = 1; off < 16; off <<= 1) {
            s  += __shfl_xor(s, off);
            s2 += __shfl_xor(s2, off);
        }
        float mean = s * (1.0f / 64.0f);
        float var  = s2 * (1.0f / 64.0f) - mean * mean;
        float rstd = rsqrtf(var + 1e-12f);
        float* orow = outp + (size_t)(bh * SEQ + q0 + qrow_loc + r) * 64;
        #pragma unroll
        for (int nt = 0; nt < 4; ++nt)
            orow[nt * 16 + l16] = (acc[nt][r] - mean) * rstd * g[nt] + bt[nt];
    }
}

// ================= fallback (round-2 kernel — proven) =================
#define KROW 72
#define SROW 40
__global__ __launch_bounds__(256, 4)
void normattn_fallback(const float* __restrict__ qp, const float* __restrict__ kp,
                       const float* __restrict__ vp, const int* __restrict__ maskp,
                       const float* __restrict__ gammap, const float* __restrict__ betap,
                       float* __restrict__ outp)
{
    __shared__ __attribute__((aligned(16))) __bf16 sQ[64 * KROW];
    __shared__ __attribute__((aligned(16))) __bf16 sK[64 * KROW];
    __shared__ __attribute__((aligned(16))) __bf16 sV[64 * KROW];
    __shared__ __attribute__((aligned(16))) __bf16 sS[4][16 * SROW];
    __shared__ __attribute__((aligned(8)))  unsigned int sMw[64][2];

    const int tid = threadIdx.x, wave = tid >> 6, lane = tid & 63;
    const int quad = lane >> 4, l16 = lane & 15;
    const int q0 = blockIdx.x * 64, bh = blockIdx.y;
    const int base = bh * SEQ * HD;
    {
        const floatx4* qg = (const floatx4*)(qp + base + q0 * HD);
        #pragma unroll
        for (int it = 0; it < 4; ++it) {
            int idx = tid + it * 256, r = idx >> 4, c = idx & 15;
            floatx4 val = qg[idx];
            bf16x4 pk = {(__bf16)val[0], (__bf16)val[1], (__bf16)val[2], (__bf16)val[3]};
            *(bf16x4*)&sQ[r * KROW + c * 4] = pk;
        }
    }
    __syncthreads();
    bfrag8 qa0 = *(const bfrag8*)&sQ[(wave * 16 + l16) * KROW + quad * 8];
    bfrag8 qa1 = *(const bfrag8*)&sQ[(wave * 16 + l16) * KROW + quad * 8 + 32];
    floatx4 acc[4];
    #pragma unroll
    for (int i = 0; i < 4; ++i) acc[i] = (floatx4)0.0f;
    const int qrow_loc = wave * 16 + quad * 4;
    const int qrb = q0 + qrow_loc;
    for (int kb = 0; kb < SEQ; kb += 64) {
        __syncthreads();
        {
            const floatx4* kg = (const floatx4*)(kp + base + kb * HD);
            #pragma unroll
            for (int it = 0; it < 4; ++it) {
                int idx = tid + it * 256, r = idx >> 4, c = idx & 15;
                floatx4 val = kg[idx];
                bf16x4 pk = {(__bf16)val[0], (__bf16)val[1], (__bf16)val[2], (__bf16)val[3]};
                *(bf16x4*)&sK[r * KROW + c * 4] = pk;
            }
        }
        {
            int d = tid & 63;
            #pragma unroll
            for (int it = 0; it < 4; ++it) {
                int k4 = (tid >> 6) + it * 4;
                bf16x4 pk;
                #pragma unroll
                for (int i = 0; i < 4; ++i) pk[i] = (__bf16)vp[base + (kb + k4 * 4 + i) * HD + d];
                *(bf16x4*)&sV[d * KROW + k4 * 4] = pk;
            }
        }
        #pragma unroll
        for (int it = 0; it < 16; ++it) {
            int rr = it * 4 + wave;
            unsigned long long bl = __ballot(maskp[(q0 + rr) * SEQ + kb + lane] != 0);
            if (lane == 0) { sMw[rr][0] = (unsigned)bl; sMw[rr][1] = (unsigned)(bl >> 32); }
        }
        __syncthreads();
        unsigned long long mrow[4];
        #pragma unroll
        for (int r = 0; r < 4; ++r) mrow[r] = *(const unsigned long long*)&sMw[qrow_loc + r][0];
        #pragma unroll
        for (int kc = 0; kc < 64; kc += 32) {
            floatx4 s0 = (floatx4)0.0f, s1 = (floatx4)0.0f;
            bfrag8 b00 = *(const bfrag8*)&sK[(kc + l16) * KROW + quad * 8];
            bfrag8 b01 = *(const bfrag8*)&sK[(kc + l16) * KROW + quad * 8 + 32];
            bfrag8 b10 = *(const bfrag8*)&sK[(kc + 16 + l16) * KROW + quad * 8];
            bfrag8 b11 = *(const bfrag8*)&sK[(kc + 16 + l16) * KROW + quad * 8 + 32];
            s0 = mfma_16x16x32(qa0, b00, s0);
            s0 = mfma_16x16x32(qa1, b01, s0);
            s1 = mfma_16x16x32(qa0, b10, s1);
            s1 = mfma_16x16x32(qa1, b11, s1);
            #pragma unroll
            for (int r = 0; r < 4; ++r) {
                float v0 = ((mrow[r] >> (kc + l16)) & 1ull) ? s0[r] : -10000.0f;
                float v1 = ((mrow[r] >> (kc + 16 + l16)) & 1ull) ? s1[r] : -10000.0f;
                sS[wave][(quad * 4 + r) * SROW + l16] = (__bf16)v0;
                sS[wave][(quad * 4 + r) * SROW + 16 + l16] = (__bf16)v1;
            }
            asm volatile("s_waitcnt lgkmcnt(0)" ::: "memory");
            bfrag8 pa = *(const bfrag8*)&sS[wave][l16 * SROW + quad * 8];
            #pragma unroll
            for (int nt = 0; nt < 4; ++nt) {
                bfrag8 vb = *(const bfrag8*)&sV[(nt * 16 + l16) * KROW + kc + quad * 8];
                acc[nt] = mfma_16x16x32(pa, vb, acc[nt]);
            }
        }
    }
    float g[4], bt[4];
    #pragma unroll
    for (int nt = 0; nt < 4; ++nt) { g[nt] = gammap[nt * 16 + l16]; bt[nt] = betap[nt * 16 + l16]; }
    #pragma unroll
    for (int r = 0; r < 4; ++r) {
        float s = 0.0f, s2 = 0.0f;
        #pragma unroll
        for (int nt = 0; nt < 4; ++nt) { float xx = acc[nt][r]; s += xx; s2 += xx * xx; }
        #pragma unroll
        for (int off = 1; off < 16; off <<= 1) { s += __shfl_xor(s, off); s2 += __shfl_xor(s2, off); }
        float mean = s * (1.0f / 64.0f);
        float var = s2 * (1.0f / 64.0f) - mean * mean;
        float rstd = rsqrtf(var + 1e-12f);
        float* orow = outp + base + (qrb + r) * HD;
        #pragma unroll
        for (int nt = 0; nt < 4; ++nt)
            orow[nt * 16 + l16] = (acc[nt][r] - mean) * rstd * g[nt] + bt[nt];
    }
}

extern "C" void kernel_launch(void* const* d_in, const int* in_sizes, int n_in,
                              void* d_out, int out_size, void* d_ws, size_t ws_size,
                              hipStream_t stream) {
    const float* q     = (const float*)d_in[0];
    const float* k     = (const float*)d_in[1];
    const float* v     = (const float*)d_in[2];
    const int*   mask  = (const int*)d_in[3];
    const float* gamma = (const float*)d_in[4];
    const float* beta  = (const float*)d_in[5];
    float* out = (float*)d_out;

    dim3 grid(32, NBH);
    if (ws_size >= WS_NEED) {
        unsigned char* ws = (unsigned char*)d_ws;
        prep_kernel<<<3328, 256, 0, stream>>>(q, k, v, mask, ws);
        normattn_main<<<grid, 256, 0, stream>>>(ws, gamma, beta, out);
    } else {
        normattn_fallback<<<grid, 256, 0, stream>>>(q, k, v, mask, gamma, beta, out);
    }
}

// Round 8
// 151.381 us; speedup vs baseline: 1.5340x; 1.5340x over previous
//
#include <hip/hip_runtime.h>

#define SEQ 2048
#define HD 64
#define NBH 24
#define ROWB 144   // padded LDS row stride in bytes (72 bf16)

// ---------------- workspace layout (proven rounds 5/6/7) ----------------
#define MB_OFF   0
#define MB_BYTES (32 * 32 * 512)                 // 512 KB: [qtb][kt][64 q-rows][u64 of k-bits]
#define QB_OFF   (MB_OFF + MB_BYTES)
#define QK_BYTES (NBH * SEQ * HD * 2)            // 6 MB bf16, plain 128B rows
#define KB_OFF   (QB_OFF + QK_BYTES)
#define VT_OFF   (KB_OFF + QK_BYTES)             // V^T pre-tiled: [bh][kt] 8KB tiles, d-major 128B rows
#define WS_NEED  ((size_t)(VT_OFF + QK_BYTES))   // ~18.5 MB

typedef __bf16 bfrag8 __attribute__((ext_vector_type(8)));
typedef __bf16 bf16x4 __attribute__((ext_vector_type(4)));
typedef float  floatx4 __attribute__((ext_vector_type(4)));

__device__ __forceinline__ floatx4 mfma_16x16x32(bfrag8 a, bfrag8 b, floatx4 c) {
    return __builtin_amdgcn_mfma_f32_16x16x32_bf16(a, b, c, 0, 0, 0);
}

// ================= prepass (byte-identical to rounds 5/6/7 — proven) =================
__global__ __launch_bounds__(256)
void prep_kernel(const float* __restrict__ qp, const float* __restrict__ kp,
                 const float* __restrict__ vp, const int* __restrict__ maskp,
                 unsigned char* __restrict__ ws)
{
    __shared__ __attribute__((aligned(16))) unsigned char parena[64 * 68 * 4];
    const int t = threadIdx.x;
    const int b = blockIdx.x;

    if (b < 1536) {
        int gt  = b * 256 + t;
        int row = gt >> 3;
        int c   = gt & 7;
        const floatx4* qs = (const floatx4*)(qp + row * 64 + c * 8);
        const floatx4* ks = (const floatx4*)(kp + row * 64 + c * 8);
        floatx4 q0 = qs[0], q1 = qs[1];
        floatx4 k0 = ks[0], k1 = ks[1];
        bfrag8 qpk, kpk;
        #pragma unroll
        for (int i = 0; i < 4; ++i) {
            qpk[i] = (__bf16)q0[i]; qpk[4 + i] = (__bf16)q1[i];
            kpk[i] = (__bf16)k0[i]; kpk[4 + i] = (__bf16)k1[i];
        }
        *(bfrag8*)(ws + QB_OFF + row * 128 + c * 16) = qpk;
        *(bfrag8*)(ws + KB_OFF + row * 128 + c * 16) = kpk;
    } else if (b < 2304) {
        int bb = b - 1536, bh = bb >> 5, kt = bb & 31;
        float* lf = (float*)parena;                 // [64 k][68 d]
        const floatx4* vg = (const floatx4*)(vp + (bh * SEQ + kt * 64) * 64);
        #pragma unroll
        for (int it = 0; it < 4; ++it) {
            int f = t + it * 256;
            int r = f >> 4, c4 = f & 15;
            floatx4 val = vg[f];
            #pragma unroll
            for (int i = 0; i < 4; ++i) lf[r * 68 + c4 * 4 + i] = val[i];
        }
        __syncthreads();
        int d = t >> 2, kseg = t & 3;
        unsigned char* tb = ws + VT_OFF + (size_t)(bh * 32 + kt) * 8192 + d * 128;
        #pragma unroll
        for (int jj = 0; jj < 2; ++jj) {
            bfrag8 pk;
            #pragma unroll
            for (int e = 0; e < 8; ++e)
                pk[e] = (__bf16)lf[(kseg * 16 + jj * 8 + e) * 68 + d];
            *(bfrag8*)(tb + (kseg * 2 + jj) * 16) = pk;
        }
    } else {
        int cc = b - 2304, qtb = cc >> 5, kt = cc & 31;
        const int w = t >> 6, lane = t & 63;
        #pragma unroll
        for (int it = 0; it < 16; ++it) {
            int rr = it * 4 + w;
            unsigned long long bl = __ballot(maskp[(qtb * 64 + rr) * SEQ + kt * 64 + lane] != 0);
            if (lane == 0)
                *(unsigned long long*)(ws + MB_OFF + (size_t)((qtb * 32 + kt) * 64 + rr) * 8) = bl;
        }
    }
}

// ======== main: round-6 register-staged LDS dbuf + round-7 k-split compute core ========
__global__ __launch_bounds__(256, 3)
void normattn_main(const unsigned char* __restrict__ ws,
                   const float* __restrict__ gammap, const float* __restrict__ betap,
                   float* __restrict__ outp)
{
    __shared__ __attribute__((aligned(16))) unsigned char sK[2][64 * ROWB];
    __shared__ __attribute__((aligned(16))) unsigned char sV[2][64 * ROWB];
    __shared__ __attribute__((aligned(16))) unsigned char sS[64 * ROWB];

    const int tid  = threadIdx.x;
    const int w    = tid >> 6;
    const int lane = tid & 63;
    const int quad = lane >> 4;
    const int l16  = lane & 15;
    const int qtb  = blockIdx.x;
    const int bh   = blockIdx.y;
    const int q0   = qtb * 64;

    const unsigned char* gKb = ws + KB_OFF + (size_t)(bh * SEQ) * 128;
    const unsigned char* gVb = ws + VT_OFF + (size_t)(bh * 32) * 8192;
    const unsigned char* gMb = ws + MB_OFF + (size_t)(qtb * 32) * 512;

    // Q fragments as B-operand, register-resident (round-7-proven addressing)
    bfrag8 qb[4][2];
    #pragma unroll
    for (int qt = 0; qt < 4; ++qt) {
        const unsigned char* gQ = ws + QB_OFF + (size_t)(bh * SEQ + q0 + qt * 16 + l16) * 128 + quad * 16;
        qb[qt][0] = *(const bfrag8*)gQ;
        qb[qt][1] = *(const bfrag8*)(gQ + 64);
    }

    floatx4 acc[4];   // acc[nt][r] = O[q = q0 + w*16 + quad*4 + r][d = nt*16 + l16]
    #pragma unroll
    for (int i = 0; i < 4; ++i) acc[i] = (floatx4)0.0f;
    const int qrow_loc = w * 16 + quad * 4;

    // staging (round-6-proven): 512 x 16B chunks per tile, 2 per thread
    const int sr0 = tid >> 3, sc0 = tid & 7;
    const int sr1 = (tid + 256) >> 3, sc1 = tid & 7;

    auto load_tile = [&](int kt, bfrag8 (&kr)[2], bfrag8 (&vr)[2]) {
        const unsigned char* gK = gKb + (size_t)kt * 8192;
        const unsigned char* gV = gVb + (size_t)kt * 8192;
        kr[0] = *(const bfrag8*)(gK + tid * 16);
        kr[1] = *(const bfrag8*)(gK + (tid + 256) * 16);
        vr[0] = *(const bfrag8*)(gV + tid * 16);
        vr[1] = *(const bfrag8*)(gV + (tid + 256) * 16);
    };
    auto write_tile = [&](int p, bfrag8 (&kr)[2], bfrag8 (&vr)[2]) {
        *(bfrag8*)(&sK[p][0] + sr0 * ROWB + sc0 * 16) = kr[0];
        *(bfrag8*)(&sK[p][0] + sr1 * ROWB + sc1 * 16) = kr[1];
        *(bfrag8*)(&sV[p][0] + sr0 * ROWB + sc0 * 16) = vr[0];
        *(bfrag8*)(&sV[p][0] + sr1 * ROWB + sc1 * 16) = vr[1];
    };

    {   // prologue: stage tile 0 + mask words for kt 0
        bfrag8 kr[2], vr[2];
        load_tile(0, kr, vr);
        write_tile(0, kr, vr);
    }
    unsigned long long mr[4];
    #pragma unroll
    for (int qt = 0; qt < 4; ++qt)
        mr[qt] = *(const unsigned long long*)(gMb + (qt * 16 + l16) * 8);
    __syncthreads();

    for (int kt = 0; kt < 32; ++kt) {
        const int p = kt & 1;

        bfrag8 kr[2], vr[2];
        if (kt < 31) load_tile(kt + 1, kr, vr);         // global loads in flight over compute
        const int ktn = (kt < 31) ? kt + 1 : 31;
        unsigned long long mrn[4];
        #pragma unroll
        for (int qt = 0; qt < 4; ++qt)
            mrn[qt] = *(const unsigned long long*)(gMb + (size_t)ktn * 512 + (qt * 16 + l16) * 8);

        const unsigned char* cK = &sK[p][0];
        const unsigned char* cV = &sV[p][0];

        // K A-frags for this wave's 16-k slice, from staged LDS (round-6 layout, round-7 slice)
        bfrag8 ka0 = *(const bfrag8*)(cK + (w * 16 + l16) * ROWB + quad * 16);
        bfrag8 ka1 = *(const bfrag8*)(cK + (w * 16 + l16) * ROWB + 64 + quad * 16);

        // ---- QK^T k-split, swapped operands (round-7-proven) ----
        #pragma unroll
        for (int qt = 0; qt < 4; ++qt) {
            floatx4 st = (floatx4)0.0f;
            st = mfma_16x16x32(ka0, qb[qt][0], st);
            st = mfma_16x16x32(ka1, qb[qt][1], st);
            unsigned long long m4 = mr[qt] >> (w * 16 + quad * 4);
            bf16x4 pk;
            #pragma unroll
            for (int r = 0; r < 4; ++r) {
                float v = ((m4 >> r) & 1ull) ? st[r] : -10000.0f;
                pk[r] = (__bf16)v;
            }
            *(bf16x4*)(sS + (qt * 16 + l16) * ROWB + w * 32 + quad * 8) = pk;   // one b64/qt
        }
        asm volatile("s_waitcnt lgkmcnt(0)" ::: "memory");
        asm volatile("s_barrier" ::: "memory");

        // ---- PV (round-7-proven addressing; vb from staged LDS) ----
        #pragma unroll
        for (int kc2 = 0; kc2 < 2; ++kc2) {
            bfrag8 pa = *(const bfrag8*)(sS + (w * 16 + l16) * ROWB + kc2 * 64 + quad * 16);
            #pragma unroll
            for (int nt = 0; nt < 4; ++nt) {
                bfrag8 vb = *(const bfrag8*)(cV + (nt * 16 + l16) * ROWB + kc2 * 64 + quad * 16);
                acc[nt] = mfma_16x16x32(pa, vb, acc[nt]);
            }
        }

        if (kt < 31) write_tile(p ^ 1, kr, vr);
        asm volatile("s_waitcnt lgkmcnt(0)" ::: "memory");
        asm volatile("s_barrier" ::: "memory");

        #pragma unroll
        for (int qt = 0; qt < 4; ++qt) mr[qt] = mrn[qt];
    }

    // ---- LayerNorm epilogue (round-6-proven, verbatim) ----
    float g[4], bt[4];
    #pragma unroll
    for (int nt = 0; nt < 4; ++nt) {
        g[nt]  = gammap[nt * 16 + l16];
        bt[nt] = betap[nt * 16 + l16];
    }
    #pragma unroll
    for (int r = 0; r < 4; ++r) {
        float s = 0.0f, s2 = 0.0f;
        #pragma unroll
        for (int nt = 0; nt < 4; ++nt) { float x = acc[nt][r]; s += x; s2 += x * x; }
        #pragma unroll
        for (int off = 1; off < 16; off <<= 1) {
            s  += __shfl_xor(s, off);
            s2 += __shfl_xor(s2, off);
        }
        float mean = s * (1.0f / 64.0f);
        float var  = s2 * (1.0f / 64.0f) - mean * mean;
        float rstd = rsqrtf(var + 1e-12f);
        float* orow = outp + (size_t)(bh * SEQ + q0 + qrow_loc + r) * 64;
        #pragma unroll
        for (int nt = 0; nt < 4; ++nt)
            orow[nt * 16 + l16] = (acc[nt][r] - mean) * rstd * g[nt] + bt[nt];
    }
}

// ================= fallback (round-2 kernel — proven) =================
#define KROW 72
#define SROW 40
__global__ __launch_bounds__(256, 4)
void normattn_fallback(const float* __restrict__ qp, const float* __restrict__ kp,
                       const float* __restrict__ vp, const int* __restrict__ maskp,
                       const float* __restrict__ gammap, const float* __restrict__ betap,
                       float* __restrict__ outp)
{
    __shared__ __attribute__((aligned(16))) __bf16 sQ[64 * KROW];
    __shared__ __attribute__((aligned(16))) __bf16 sK[64 * KROW];
    __shared__ __attribute__((aligned(16))) __bf16 sV[64 * KROW];
    __shared__ __attribute__((aligned(16))) __bf16 sS[4][16 * SROW];
    __shared__ __attribute__((aligned(8)))  unsigned int sMw[64][2];

    const int tid = threadIdx.x, wave = tid >> 6, lane = tid & 63;
    const int quad = lane >> 4, l16 = lane & 15;
    const int q0 = blockIdx.x * 64, bh = blockIdx.y;
    const int base = bh * SEQ * HD;
    {
        const floatx4* qg = (const floatx4*)(qp + base + q0 * HD);
        #pragma unroll
        for (int it = 0; it < 4; ++it) {
            int idx = tid + it * 256, r = idx >> 4, c = idx & 15;
            floatx4 val = qg[idx];
            bf16x4 pk = {(__bf16)val[0], (__bf16)val[1], (__bf16)val[2], (__bf16)val[3]};
            *(bf16x4*)&sQ[r * KROW + c * 4] = pk;
        }
    }
    __syncthreads();
    bfrag8 qa0 = *(const bfrag8*)&sQ[(wave * 16 + l16) * KROW + quad * 8];
    bfrag8 qa1 = *(const bfrag8*)&sQ[(wave * 16 + l16) * KROW + quad * 8 + 32];
    floatx4 acc[4];
    #pragma unroll
    for (int i = 0; i < 4; ++i) acc[i] = (floatx4)0.0f;
    const int qrow_loc = wave * 16 + quad * 4;
    const int qrb = q0 + qrow_loc;
    for (int kb = 0; kb < SEQ; kb += 64) {
        __syncthreads();
        {
            const floatx4* kg = (const floatx4*)(kp + base + kb * HD);
            #pragma unroll
            for (int it = 0; it < 4; ++it) {
                int idx = tid + it * 256, r = idx >> 4, c = idx & 15;
                floatx4 val = kg[idx];
                bf16x4 pk = {(__bf16)val[0], (__bf16)val[1], (__bf16)val[2], (__bf16)val[3]};
                *(bf16x4*)&sK[r * KROW + c * 4] = pk;
            }
        }
        {
            int d = tid & 63;
            #pragma unroll
            for (int it = 0; it < 4; ++it) {
                int k4 = (tid >> 6) + it * 4;
                bf16x4 pk;
                #pragma unroll
                for (int i = 0; i < 4; ++i) pk[i] = (__bf16)vp[base + (kb + k4 * 4 + i) * HD + d];
                *(bf16x4*)&sV[d * KROW + k4 * 4] = pk;
            }
        }
        #pragma unroll
        for (int it = 0; it < 16; ++it) {
            int rr = it * 4 + wave;
            unsigned long long bl = __ballot(maskp[(q0 + rr) * SEQ + kb + lane] != 0);
            if (lane == 0) { sMw[rr][0] = (unsigned)bl; sMw[rr][1] = (unsigned)(bl >> 32); }
        }
        __syncthreads();
        unsigned long long mrow[4];
        #pragma unroll
        for (int r = 0; r < 4; ++r) mrow[r] = *(const unsigned long long*)&sMw[qrow_loc + r][0];
        #pragma unroll
        for (int kc = 0; kc < 64; kc += 32) {
            floatx4 s0 = (floatx4)0.0f, s1 = (floatx4)0.0f;
            bfrag8 b00 = *(const bfrag8*)&sK[(kc + l16) * KROW + quad * 8];
            bfrag8 b01 = *(const bfrag8*)&sK[(kc + l16) * KROW + quad * 8 + 32];
            bfrag8 b10 = *(const bfrag8*)&sK[(kc + 16 + l16) * KROW + quad * 8];
            bfrag8 b11 = *(const bfrag8*)&sK[(kc + 16 + l16) * KROW + quad * 8 + 32];
            s0 = mfma_16x16x32(qa0, b00, s0);
            s0 = mfma_16x16x32(qa1, b01, s0);
            s1 = mfma_16x16x32(qa0, b10, s1);
            s1 = mfma_16x16x32(qa1, b11, s1);
            #pragma unroll
            for (int r = 0; r < 4; ++r) {
                float v0 = ((mrow[r] >> (kc + l16)) & 1ull) ? s0[r] : -10000.0f;
                float v1 = ((mrow[r] >> (kc + 16 + l16)) & 1ull) ? s1[r] : -10000.0f;
                sS[wave][(quad * 4 + r) * SROW + l16] = (__bf16)v0;
                sS[wave][(quad * 4 + r) * SROW + 16 + l16] = (__bf16)v1;
            }
            asm volatile("s_waitcnt lgkmcnt(0)" ::: "memory");
            bfrag8 pa = *(const bfrag8*)&sS[wave][l16 * SROW + quad * 8];
            #pragma unroll
            for (int nt = 0; nt < 4; ++nt) {
                bfrag8 vb = *(const bfrag8*)&sV[(nt * 16 + l16) * KROW + kc + quad * 8];
                acc[nt] = mfma_16x16x32(pa, vb, acc[nt]);
            }
        }
    }
    float g[4], bt[4];
    #pragma unroll
    for (int nt = 0; nt < 4; ++nt) { g[nt] = gammap[nt * 16 + l16]; bt[nt] = betap[nt * 16 + l16]; }
    #pragma unroll
    for (int r = 0; r < 4; ++r) {
        float s = 0.0f, s2 = 0.0f;
        #pragma unroll
        for (int nt = 0; nt < 4; ++nt) { float xx = acc[nt][r]; s += xx; s2 += xx * xx; }
        #pragma unroll
        for (int off = 1; off < 16; off <<= 1) { s += __shfl_xor(s, off); s2 += __shfl_xor(s2, off); }
        float mean = s * (1.0f / 64.0f);
        float var = s2 * (1.0f / 64.0f) - mean * mean;
        float rstd = rsqrtf(var + 1e-12f);
        float* orow = outp + base + (qrb + r) * HD;
        #pragma unroll
        for (int nt = 0; nt < 4; ++nt)
            orow[nt * 16 + l16] = (acc[nt][r] - mean) * rstd * g[nt] + bt[nt];
    }
}

extern "C" void kernel_launch(void* const* d_in, const int* in_sizes, int n_in,
                              void* d_out, int out_size, void* d_ws, size_t ws_size,
                              hipStream_t stream) {
    const float* q     = (const float*)d_in[0];
    const float* k     = (const float*)d_in[1];
    const float* v     = (const float*)d_in[2];
    const int*   mask  = (const int*)d_in[3];
    const float* gamma = (const float*)d_in[4];
    const float* beta  = (const float*)d_in[5];
    float* out = (float*)d_out;

    dim3 grid(32, NBH);
    if (ws_size >= WS_NEED) {
        unsigned char* ws = (unsigned char*)d_ws;
        prep_kernel<<<3328, 256, 0, stream>>>(q, k, v, mask, ws);
        normattn_main<<<grid, 256, 0, stream>>>(ws, gamma, beta, out);
    } else {
        normattn_fallback<<<grid, 256, 0, stream>>>(q, k, v, mask, gamma, beta, out);
    }
}

// Round 9
// 147.722 us; speedup vs baseline: 1.5720x; 1.0248x over previous
//
#include <hip/hip_runtime.h>

#define SEQ 2048
#define HD 64
#define NBH 24
#define ROWB 144   // padded K/V LDS row stride in bytes (72 bf16, proven)

// ---------------- workspace layout (proven rounds 5-8) ----------------
#define MB_OFF   0
#define MB_BYTES (32 * 32 * 512)                 // 512 KB: [qtb][kt][64 q-rows][u64 of k-bits]
#define QB_OFF   (MB_OFF + MB_BYTES)
#define QK_BYTES (NBH * SEQ * HD * 2)            // 6 MB bf16, plain 128B rows
#define KB_OFF   (QB_OFF + QK_BYTES)
#define VT_OFF   (KB_OFF + QK_BYTES)             // V^T pre-tiled: [bh][kt] 8KB tiles, d-major 128B rows
#define WS_NEED  ((size_t)(VT_OFF + QK_BYTES))   // ~18.5 MB

typedef __bf16 bfrag8 __attribute__((ext_vector_type(8)));
typedef __bf16 bf16x4 __attribute__((ext_vector_type(4)));
typedef float  floatx4 __attribute__((ext_vector_type(4)));

__device__ __forceinline__ floatx4 mfma_16x16x32(bfrag8 a, bfrag8 b, floatx4 c) {
    return __builtin_amdgcn_mfma_f32_16x16x32_bf16(a, b, c, 0, 0, 0);
}

// ================= prepass (byte-identical to rounds 5-8 — proven) =================
__global__ __launch_bounds__(256)
void prep_kernel(const float* __restrict__ qp, const float* __restrict__ kp,
                 const float* __restrict__ vp, const int* __restrict__ maskp,
                 unsigned char* __restrict__ ws)
{
    __shared__ __attribute__((aligned(16))) unsigned char parena[64 * 68 * 4];
    const int t = threadIdx.x;
    const int b = blockIdx.x;

    if (b < 1536) {
        int gt  = b * 256 + t;
        int row = gt >> 3;
        int c   = gt & 7;
        const floatx4* qs = (const floatx4*)(qp + row * 64 + c * 8);
        const floatx4* ks = (const floatx4*)(kp + row * 64 + c * 8);
        floatx4 q0 = qs[0], q1 = qs[1];
        floatx4 k0 = ks[0], k1 = ks[1];
        bfrag8 qpk, kpk;
        #pragma unroll
        for (int i = 0; i < 4; ++i) {
            qpk[i] = (__bf16)q0[i]; qpk[4 + i] = (__bf16)q1[i];
            kpk[i] = (__bf16)k0[i]; kpk[4 + i] = (__bf16)k1[i];
        }
        *(bfrag8*)(ws + QB_OFF + row * 128 + c * 16) = qpk;
        *(bfrag8*)(ws + KB_OFF + row * 128 + c * 16) = kpk;
    } else if (b < 2304) {
        int bb = b - 1536, bh = bb >> 5, kt = bb & 31;
        float* lf = (float*)parena;                 // [64 k][68 d]
        const floatx4* vg = (const floatx4*)(vp + (bh * SEQ + kt * 64) * 64);
        #pragma unroll
        for (int it = 0; it < 4; ++it) {
            int f = t + it * 256;
            int r = f >> 4, c4 = f & 15;
            floatx4 val = vg[f];
            #pragma unroll
            for (int i = 0; i < 4; ++i) lf[r * 68 + c4 * 4 + i] = val[i];
        }
        __syncthreads();
        int d = t >> 2, kseg = t & 3;
        unsigned char* tb = ws + VT_OFF + (size_t)(bh * 32 + kt) * 8192 + d * 128;
        #pragma unroll
        for (int jj = 0; jj < 2; ++jj) {
            bfrag8 pk;
            #pragma unroll
            for (int e = 0; e < 8; ++e)
                pk[e] = (__bf16)lf[(kseg * 16 + jj * 8 + e) * 68 + d];
            *(bfrag8*)(tb + (kseg * 2 + jj) * 16) = pk;
        }
    } else {
        int cc = b - 2304, qtb = cc >> 5, kt = cc & 31;
        const int w = t >> 6, lane = t & 63;
        #pragma unroll
        for (int it = 0; it < 16; ++it) {
            int rr = it * 4 + w;
            unsigned long long bl = __ballot(maskp[(qtb * 64 + rr) * SEQ + kt * 64 + lane] != 0);
            if (lane == 0)
                *(unsigned long long*)(ws + MB_OFF + (size_t)((qtb * 32 + kt) * 64 + rr) * 8) = bl;
        }
    }
}

// ======== main: 2-kt super-iteration, register-staged single-buffer, 3 barriers / 2 kt ========
__global__ __launch_bounds__(256, 3)
void normattn_main(const unsigned char* __restrict__ ws,
                   const float* __restrict__ gammap, const float* __restrict__ betap,
                   float* __restrict__ outp)
{
    __shared__ __attribute__((aligned(16))) unsigned char sK[2][64 * ROWB];   // slot = tile parity
    __shared__ __attribute__((aligned(16))) unsigned char sV[2][64 * ROWB];
    __shared__ __attribute__((aligned(16))) unsigned char sS[2][64 * 128];    // unpadded + XOR swizzle

    const int tid  = threadIdx.x;
    const int w    = tid >> 6;
    const int lane = tid & 63;
    const int quad = lane >> 4;
    const int l16  = lane & 15;
    const int qtb  = blockIdx.x;
    const int bh   = blockIdx.y;
    const int q0   = qtb * 64;
    const int swz  = l16 & 7;                      // per-row chunk swizzle key for sS

    const unsigned char* gKb = ws + KB_OFF + (size_t)(bh * SEQ) * 128;
    const unsigned char* gVb = ws + VT_OFF + (size_t)(bh * 32) * 8192;
    const unsigned char* gMb = ws + MB_OFF + (size_t)(qtb * 32) * 512;

    // Q fragments as B-operand, register-resident (rounds 7/8 proven)
    bfrag8 qb[4][2];
    #pragma unroll
    for (int qt = 0; qt < 4; ++qt) {
        const unsigned char* gQ = ws + QB_OFF + (size_t)(bh * SEQ + q0 + qt * 16 + l16) * 128 + quad * 16;
        qb[qt][0] = *(const bfrag8*)gQ;
        qb[qt][1] = *(const bfrag8*)(gQ + 64);
    }

    floatx4 acc[4];   // acc[nt][r] = O[q = q0 + w*16 + quad*4 + r][d = nt*16 + l16]
    #pragma unroll
    for (int i = 0; i < 4; ++i) acc[i] = (floatx4)0.0f;
    const int qrow_loc = w * 16 + quad * 4;

    // staging (round-6/8 proven): 512 x 16B chunks per tile, 2 per thread per matrix
    const int sr0 = tid >> 3, sc0 = tid & 7;
    const int sr1 = (tid + 256) >> 3, sc1 = tid & 7;

    auto load_tile = [&](int kt, bfrag8 (&kr)[2], bfrag8 (&vr)[2]) {
        const unsigned char* gK = gKb + (size_t)kt * 8192;
        const unsigned char* gV = gVb + (size_t)kt * 8192;
        kr[0] = *(const bfrag8*)(gK + tid * 16);
        kr[1] = *(const bfrag8*)(gK + (tid + 256) * 16);
        vr[0] = *(const bfrag8*)(gV + tid * 16);
        vr[1] = *(const bfrag8*)(gV + (tid + 256) * 16);
    };
    auto write_tile = [&](int s, bfrag8 (&kr)[2], bfrag8 (&vr)[2]) {
        *(bfrag8*)(&sK[s][0] + sr0 * ROWB + sc0 * 16) = kr[0];
        *(bfrag8*)(&sK[s][0] + sr1 * ROWB + sc1 * 16) = kr[1];
        *(bfrag8*)(&sV[s][0] + sr0 * ROWB + sc0 * 16) = vr[0];
        *(bfrag8*)(&sV[s][0] + sr1 * ROWB + sc1 * 16) = vr[1];
    };

    // QK k-split + mask + swizzled b64 bridge (rounds 7/8 proven math; sS layout re-derived)
    auto qk_phase = [&](int tt, const unsigned char* cK, const unsigned long long (&mr)[4]) {
        bfrag8 ka0 = *(const bfrag8*)(cK + (w * 16 + l16) * ROWB + quad * 16);
        bfrag8 ka1 = *(const bfrag8*)(cK + (w * 16 + l16) * ROWB + 64 + quad * 16);
        #pragma unroll
        for (int qt = 0; qt < 4; ++qt) {
            floatx4 st = (floatx4)0.0f;
            st = mfma_16x16x32(ka0, qb[qt][0], st);
            st = mfma_16x16x32(ka1, qb[qt][1], st);
            unsigned long long m4 = mr[qt] >> (w * 16 + quad * 4);
            bf16x4 pk;
            #pragma unroll
            for (int r = 0; r < 4; ++r) {
                float v = ((m4 >> r) & 1ull) ? st[r] : -10000.0f;
                pk[r] = (__bf16)v;
            }
            // logical: S[q=qt*16+l16][k=w*16+quad*4 .. +3]; chunk c=w*2+(quad>>1), swizzled c^swz
            *(bf16x4*)(&sS[tt][0] + (qt * 16 + l16) * 128 +
                       (((w * 2 + (quad >> 1)) ^ swz) * 16) + (quad & 1) * 8) = pk;
        }
    };
    auto pv_phase = [&](int tt, const unsigned char* cV) {
        #pragma unroll
        for (int kc2 = 0; kc2 < 2; ++kc2) {
            bfrag8 pa = *(const bfrag8*)(&sS[tt][0] + (w * 16 + l16) * 128 +
                                         (((kc2 * 4 + quad) ^ swz) * 16));
            #pragma unroll
            for (int nt = 0; nt < 4; ++nt) {
                bfrag8 vb = *(const bfrag8*)(cV + (nt * 16 + l16) * ROWB + kc2 * 64 + quad * 16);
                acc[nt] = mfma_16x16x32(pa, vb, acc[nt]);
            }
        }
    };

    {   // prologue: stage tiles 0,1
        bfrag8 k0r[2], v0r[2], k1r[2], v1r[2];
        load_tile(0, k0r, v0r);
        load_tile(1, k1r, v1r);
        write_tile(0, k0r, v0r);
        write_tile(1, k1r, v1r);
    }
    asm volatile("s_waitcnt lgkmcnt(0)" ::: "memory");
    asm volatile("s_barrier" ::: "memory");

    for (int i = 0; i < 16; ++i) {
        const int t0 = 2 * i, t1 = 2 * i + 1;

        bfrag8 kA[2], vA[2];
        if (i < 15) load_tile(t0 + 2, kA, vA);      // prefetch A over QK phase

        unsigned long long mr0[4], mr1[4];
        #pragma unroll
        for (int qt = 0; qt < 4; ++qt) {
            mr0[qt] = *(const unsigned long long*)(gMb + (size_t)t0 * 512 + (qt * 16 + l16) * 8);
            mr1[qt] = *(const unsigned long long*)(gMb + (size_t)t1 * 512 + (qt * 16 + l16) * 8);
        }

        qk_phase(0, &sK[0][0], mr0);
        qk_phase(1, &sK[1][0], mr1);
        asm volatile("s_waitcnt lgkmcnt(0)" ::: "memory");
        asm volatile("s_barrier" ::: "memory");      // BAR_A: sS[0],sS[1] ready

        bfrag8 kB[2], vB[2];
        if (i < 15) load_tile(t0 + 3, kB, vB);      // prefetch B over PV phase

        pv_phase(0, &sV[0][0]);
        pv_phase(1, &sV[1][0]);
        asm volatile("s_waitcnt lgkmcnt(0)" ::: "memory");
        asm volatile("s_barrier" ::: "memory");      // BAR_B: all reads of sK/sV/sS done

        if (i < 15) {
            write_tile(0, kA, vA);                   // tiles 2i+2 / 2i+3 into slots
            write_tile(1, kB, vB);
        }
        asm volatile("s_waitcnt lgkmcnt(0)" ::: "memory");
        asm volatile("s_barrier" ::: "memory");      // BAR_C: new tiles visible
    }

    // ---- LayerNorm epilogue (rounds 6-8 proven, verbatim) ----
    float g[4], bt[4];
    #pragma unroll
    for (int nt = 0; nt < 4; ++nt) {
        g[nt]  = gammap[nt * 16 + l16];
        bt[nt] = betap[nt * 16 + l16];
    }
    #pragma unroll
    for (int r = 0; r < 4; ++r) {
        float s = 0.0f, s2 = 0.0f;
        #pragma unroll
        for (int nt = 0; nt < 4; ++nt) { float x = acc[nt][r]; s += x; s2 += x * x; }
        #pragma unroll
        for (int off = 1; off < 16; off <<= 1) {
            s  += __shfl_xor(s, off);
            s2 += __shfl_xor(s2, off);
        }
        float mean = s * (1.0f / 64.0f);
        float var  = s2 * (1.0f / 64.0f) - mean * mean;
        float rstd = rsqrtf(var + 1e-12f);
        float* orow = outp + (size_t)(bh * SEQ + q0 + qrow_loc + r) * 64;
        #pragma unroll
        for (int nt = 0; nt < 4; ++nt)
            orow[nt * 16 + l16] = (acc[nt][r] - mean) * rstd * g[nt] + bt[nt];
    }
}

// ================= fallback (round-2 kernel — proven) =================
#define KROW 72
#define SROW 40
__global__ __launch_bounds__(256, 4)
void normattn_fallback(const float* __restrict__ qp, const float* __restrict__ kp,
                       const float* __restrict__ vp, const int* __restrict__ maskp,
                       const float* __restrict__ gammap, const float* __restrict__ betap,
                       float* __restrict__ outp)
{
    __shared__ __attribute__((aligned(16))) __bf16 sQ[64 * KROW];
    __shared__ __attribute__((aligned(16))) __bf16 sK[64 * KROW];
    __shared__ __attribute__((aligned(16))) __bf16 sV[64 * KROW];
    __shared__ __attribute__((aligned(16))) __bf16 sS[4][16 * SROW];
    __shared__ __attribute__((aligned(8)))  unsigned int sMw[64][2];

    const int tid = threadIdx.x, wave = tid >> 6, lane = tid & 63;
    const int quad = lane >> 4, l16 = lane & 15;
    const int q0 = blockIdx.x * 64, bh = blockIdx.y;
    const int base = bh * SEQ * HD;
    {
        const floatx4* qg = (const floatx4*)(qp + base + q0 * HD);
        #pragma unroll
        for (int it = 0; it < 4; ++it) {
            int idx = tid + it * 256, r = idx >> 4, c = idx & 15;
            floatx4 val = qg[idx];
            bf16x4 pk = {(__bf16)val[0], (__bf16)val[1], (__bf16)val[2], (__bf16)val[3]};
            *(bf16x4*)&sQ[r * KROW + c * 4] = pk;
        }
    }
    __syncthreads();
    bfrag8 qa0 = *(const bfrag8*)&sQ[(wave * 16 + l16) * KROW + quad * 8];
    bfrag8 qa1 = *(const bfrag8*)&sQ[(wave * 16 + l16) * KROW + quad * 8 + 32];
    floatx4 acc[4];
    #pragma unroll
    for (int i = 0; i < 4; ++i) acc[i] = (floatx4)0.0f;
    const int qrow_loc = wave * 16 + quad * 4;
    const int qrb = q0 + qrow_loc;
    for (int kb = 0; kb < SEQ; kb += 64) {
        __syncthreads();
        {
            const floatx4* kg = (const floatx4*)(kp + base + kb * HD);
            #pragma unroll
            for (int it = 0; it < 4; ++it) {
                int idx = tid + it * 256, r = idx >> 4, c = idx & 15;
                floatx4 val = kg[idx];
                bf16x4 pk = {(__bf16)val[0], (__bf16)val[1], (__bf16)val[2], (__bf16)val[3]};
                *(bf16x4*)&sK[r * KROW + c * 4] = pk;
            }
        }
        {
            int d = tid & 63;
            #pragma unroll
            for (int it = 0; it < 4; ++it) {
                int k4 = (tid >> 6) + it * 4;
                bf16x4 pk;
                #pragma unroll
                for (int i = 0; i < 4; ++i) pk[i] = (__bf16)vp[base + (kb + k4 * 4 + i) * HD + d];
                *(bf16x4*)&sV[d * KROW + k4 * 4] = pk;
            }
        }
        #pragma unroll
        for (int it = 0; it < 16; ++it) {
            int rr = it * 4 + wave;
            unsigned long long bl = __ballot(maskp[(q0 + rr) * SEQ + kb + lane] != 0);
            if (lane == 0) { sMw[rr][0] = (unsigned)bl; sMw[rr][1] = (unsigned)(bl >> 32); }
        }
        __syncthreads();
        unsigned long long mrow[4];
        #pragma unroll
        for (int r = 0; r < 4; ++r) mrow[r] = *(const unsigned long long*)&sMw[qrow_loc + r][0];
        #pragma unroll
        for (int kc = 0; kc < 64; kc += 32) {
            floatx4 s0 = (floatx4)0.0f, s1 = (floatx4)0.0f;
            bfrag8 b00 = *(const bfrag8*)&sK[(kc + l16) * KROW + quad * 8];
            bfrag8 b01 = *(const bfrag8*)&sK[(kc + l16) * KROW + quad * 8 + 32];
            bfrag8 b10 = *(const bfrag8*)&sK[(kc + 16 + l16) * KROW + quad * 8];
            bfrag8 b11 = *(const bfrag8*)&sK[(kc + 16 + l16) * KROW + quad * 8 + 32];
            s0 = mfma_16x16x32(qa0, b00, s0);
            s0 = mfma_16x16x32(qa1, b01, s0);
            s1 = mfma_16x16x32(qa0, b10, s1);
            s1 = mfma_16x16x32(qa1, b11, s1);
            #pragma unroll
            for (int r = 0; r < 4; ++r) {
                float v0 = ((mrow[r] >> (kc + l16)) & 1ull) ? s0[r] : -10000.0f;
                float v1 = ((mrow[r] >> (kc + 16 + l16)) & 1ull) ? s1[r] : -10000.0f;
                sS[wave][(quad * 4 + r) * SROW + l16] = (__bf16)v0;
                sS[wave][(quad * 4 + r) * SROW + 16 + l16] = (__bf16)v1;
            }
            asm volatile("s_waitcnt lgkmcnt(0)" ::: "memory");
            bfrag8 pa = *(const bfrag8*)&sS[wave][l16 * SROW + quad * 8];
            #pragma unroll
            for (int nt = 0; nt < 4; ++nt) {
                bfrag8 vb = *(const bfrag8*)&sV[(nt * 16 + l16) * KROW + kc + quad * 8];
                acc[nt] = mfma_16x16x32(pa, vb, acc[nt]);
            }
        }
    }
    float g[4], bt[4];
    #pragma unroll
    for (int nt = 0; nt < 4; ++nt) { g[nt] = gammap[nt * 16 + l16]; bt[nt] = betap[nt * 16 + l16]; }
    #pragma unroll
    for (int r = 0; r < 4; ++r) {
        float s = 0.0f, s2 = 0.0f;
        #pragma unroll
        for (int nt = 0; nt < 4; ++nt) { float xx = acc[nt][r]; s += xx; s2 += xx * xx; }
        #pragma unroll
        for (int off = 1; off < 16; off <<= 1) { s += __shfl_xor(s, off); s2 += __shfl_xor(s2, off); }
        float mean = s * (1.0f / 64.0f);
        float var = s2 * (1.0f / 64.0f) - mean * mean;
        float rstd = rsqrtf(var + 1e-12f);
        float* orow = outp + base + (qrb + r) * HD;
        #pragma unroll
        for (int nt = 0; nt < 4; ++nt)
            orow[nt * 16 + l16] = (acc[nt][r] - mean) * rstd * g[nt] + bt[nt];
    }
}

extern "C" void kernel_launch(void* const* d_in, const int* in_sizes, int n_in,
                              void* d_out, int out_size, void* d_ws, size_t ws_size,
                              hipStream_t stream) {
    const float* q     = (const float*)d_in[0];
    const float* k     = (const float*)d_in[1];
    const float* v     = (const float*)d_in[2];
    const int*   mask  = (const int*)d_in[3];
    const float* gamma = (const float*)d_in[4];
    const float* beta  = (const float*)d_in[5];
    float* out = (float*)d_out;

    dim3 grid(32, NBH);
    if (ws_size >= WS_NEED) {
        unsigned char* ws = (unsigned char*)d_ws;
        prep_kernel<<<3328, 256, 0, stream>>>(q, k, v, mask, ws);
        normattn_main<<<grid, 256, 0, stream>>>(ws, gamma, beta, out);
    } else {
        normattn_fallback<<<grid, 256, 0, stream>>>(q, k, v, mask, gamma, beta, out);
    }
}